// Round 1
// baseline (12736.550 us; speedup 1.0000x reference)
//
#include <hip/hip_runtime.h>
#include <math.h>

#define BB_ 32
#define TT_ 128
#define EE_ 64
#define HH_ 128
#define VV_ 32000
#define NMM 200      // matmul workgroups
#define NCELL 32     // cell workgroups (one per batch)
#define NWG (NMM + NCELL)
#define VW 160       // vocab rows per matmul wg (200*160 = 32000)

// ---- dynamic LDS layout (bytes) for decoder ----
#define OFF_LW   0        // float4[32*160]  = 81920   fc_w slice, [kcc][row]
#define OFF_LH   81920    // float4[32*32]   = 16384   h,        [kcc][b]
#define OFF_REDF 98304    // float[256*21]   = 21504   k-split reduce
#define OFF_PB   119808   // u64[32*33]      = 8448    per-wg argmax partials
#define OFF_R64  128256   // u64[512]        = 4096    cell-wg reduce tree
#define OFF_SG   132352   // float[512]      = 2048    gates
#define OFF_SH   134400   // float[128]      = 512     h (cell)
#define DYN_LDS  134912

// ---- workspace layout (bytes) ----
#define WS_PART  0        // u64[NMM*32] = 51200
#define WS_HDEC  51200    // float[32*128]
#define WS_HENC  67584
#define WS_CENC  83968
#define WS_MMF   100352   // unsigned[NMM] = 800
#define WS_HF    101152   // unsigned[32]  = 128
#define WS_END   101280

__device__ __forceinline__ float rlane(float v, int l){
  return __int_as_float(__builtin_amdgcn_readlane(__float_as_int(v), l));
}
__device__ __forceinline__ float sigm(float x){ return 1.f / (1.f + expf(-x)); }

__device__ __forceinline__ unsigned long long packmax(float v, int idx){
  unsigned u = __float_as_uint(v);
  u = (u & 0x80000000u) ? ~u : (u | 0x80000000u);   // monotone float->uint map
  return ((unsigned long long)u << 32) | (unsigned long long)(0xFFFFFFFFu - (unsigned)idx);
}

// gate[row=t] = bias + sum_e wih[e]*x[e] + sum_j whh[j]*h[j]; x/h broadcast via readlane
__device__ __forceinline__ float gate_dot(const float (&wih)[EE_], const float (&whh)[HH_],
                                          float bias, float xe, float h0, float h1){
  float a0 = bias, a1 = 0.f, a2 = 0.f, a3 = 0.f;
#pragma unroll
  for (int e = 0; e < EE_; e += 4){
    a0 = fmaf(wih[e+0], rlane(xe, e+0), a0);
    a1 = fmaf(wih[e+1], rlane(xe, e+1), a1);
    a2 = fmaf(wih[e+2], rlane(xe, e+2), a2);
    a3 = fmaf(wih[e+3], rlane(xe, e+3), a3);
  }
#pragma unroll
  for (int j = 0; j < 64; j += 4){
    a0 = fmaf(whh[j+0], rlane(h0, j+0), a0);
    a1 = fmaf(whh[j+1], rlane(h0, j+1), a1);
    a2 = fmaf(whh[j+2], rlane(h0, j+2), a2);
    a3 = fmaf(whh[j+3], rlane(h0, j+3), a3);
  }
#pragma unroll
  for (int j = 0; j < 64; j += 4){
    a0 = fmaf(whh[64+j+0], rlane(h1, j+0), a0);
    a1 = fmaf(whh[64+j+1], rlane(h1, j+1), a1);
    a2 = fmaf(whh[64+j+2], rlane(h1, j+2), a2);
    a3 = fmaf(whh[64+j+3], rlane(h1, j+3), a3);
  }
  return (a0 + a1) + (a2 + a3);
}

// ===================== encoder: 32 wgs (one per batch), no cross-wg deps =====================
__global__ __launch_bounds__(512)
void enc_kernel(const int* __restrict__ xt, const float* __restrict__ embed,
                const float* __restrict__ Wih, const float* __restrict__ Whh,
                const float* __restrict__ bv,
                float* __restrict__ h_out, float* __restrict__ c_out)
{
  const int b = blockIdx.x, t = threadIdx.x, lane = t & 63;
  __shared__ float sh[HH_];
  __shared__ float sg[4*HH_];
  float wih[EE_], whh[HH_];
#pragma unroll
  for (int e = 0; e < EE_; ++e) wih[e] = Wih[t*EE_ + e];
#pragma unroll
  for (int j = 0; j < HH_; ++j) whh[j] = Whh[t*HH_ + j];
  const float bias = bv[t];
  float c = 0.f, hv = 0.f;
  if (t < HH_) sh[t] = 0.f;
  __syncthreads();
#pragma unroll 1
  for (int s = 0; s < TT_; ++s){
    const int tok = xt[b*TT_ + s];
    const float xe = embed[tok*EE_ + lane];
    const float h0 = sh[lane], h1 = sh[64 + lane];
    const float g = gate_dot(wih, whh, bias, xe, h0, h1);
    sg[t] = g;
    __syncthreads();
    if (t < HH_){
      const float gi = sg[t], gf = sg[128+t], gg = sg[256+t], go = sg[384+t];
      c = sigm(gf)*c + sigm(gi)*tanhf(gg);
      hv = sigm(go)*tanhf(c);
      sh[t] = hv;
    }
    __syncthreads();
  }
  if (t < HH_){ h_out[b*HH_ + t] = hv; c_out[b*HH_ + t] = c; }
}

// ===================== decoder: persistent, 32 cell wgs + 200 matmul wgs =====================
__global__ __launch_bounds__(512)
void dec_kernel(const float* __restrict__ embed,
                const float* __restrict__ dWih, const float* __restrict__ dWhh,
                const float* __restrict__ db,
                const float* __restrict__ fcw, const float* __restrict__ fcb,
                const float* __restrict__ h_enc, const float* __restrict__ c_enc,
                float* __restrict__ h_dec, unsigned* __restrict__ mm_flag,
                unsigned* __restrict__ h_flag, unsigned long long* __restrict__ part,
                float* __restrict__ out)
{
  extern __shared__ char smem[];
  const int t = threadIdx.x;
  const int wg = blockIdx.x;

  if (wg < NCELL){
    // ---------------- cell workgroup: owns batch b ----------------
    float* sg = (float*)(smem + OFF_SG);
    float* sh = (float*)(smem + OFF_SH);
    unsigned long long* r64 = (unsigned long long*)(smem + OFF_R64);
    const int b = wg, lane = t & 63;
    float wih[EE_], whh[HH_];
#pragma unroll
    for (int e = 0; e < EE_; ++e) wih[e] = dWih[t*EE_ + e];
#pragma unroll
    for (int j = 0; j < HH_; ++j) whh[j] = dWhh[t*HH_ + j];
    const float bias = db[t];
    float c = 0.f;
    if (t < HH_){ c = c_enc[b*HH_ + t]; sh[t] = h_enc[b*HH_ + t]; }
    int tok = 1; // SOS
    __syncthreads();
#pragma unroll 1
    for (int s = 1; s <= TT_; ++s){
      const float xe = embed[tok*EE_ + lane];
      const float h0 = sh[lane], h1 = sh[64 + lane];
      const float g = gate_dot(wih, whh, bias, xe, h0, h1);
      sg[t] = g;
      __syncthreads();
      if (t < HH_){
        const float gi = sg[t], gf = sg[128+t], gg = sg[256+t], go = sg[384+t];
        c = sigm(gf)*c + sigm(gi)*tanhf(gg);
        const float hv = sigm(go)*tanhf(c);
        sh[t] = hv;
        __hip_atomic_store(&h_dec[b*HH_ + t], hv, __ATOMIC_RELAXED, __HIP_MEMORY_SCOPE_AGENT);
      }
      __threadfence();          // drain h stores to coherence point
      __syncthreads();
      if (t == 0) __hip_atomic_store(&h_flag[b], (unsigned)s, __ATOMIC_RELEASE, __HIP_MEMORY_SCOPE_AGENT);
      // wait for all matmul wgs to publish argmax partials for step s
      for (int i = t; i < NMM; i += 512)
        while (__hip_atomic_load(&mm_flag[i], __ATOMIC_ACQUIRE, __HIP_MEMORY_SCOPE_AGENT) != (unsigned)s)
          __builtin_amdgcn_s_sleep(2);
      __syncthreads();
      unsigned long long m = 0ull;
      if (t < NMM) m = __hip_atomic_load(&part[t*32 + b], __ATOMIC_RELAXED, __HIP_MEMORY_SCOPE_AGENT);
      r64[t] = m;
      __syncthreads();
#pragma unroll 1
      for (int st = 256; st > 0; st >>= 1){
        if (t < st){ const unsigned long long o = r64[t + st]; if (o > r64[t]) r64[t] = o; }
        __syncthreads();
      }
      tok = (int)(0xFFFFFFFFu - (unsigned)(r64[0] & 0xFFFFFFFFull));
    }
  } else {
    // ---------------- matmul workgroup: vocab rows [v0, v0+VW) ----------------
    const int widx = wg - NCELL;
    const int v0 = widx * VW;
    float4* lw4 = (float4*)(smem + OFF_LW);
    float4* lh4 = (float4*)(smem + OFF_LH);
    float*  rdf = (float*)(smem + OFF_REDF);
    unsigned long long* pb = (unsigned long long*)(smem + OFF_PB);
    const int ks = t >> 8;          // k-split half: [0,64) or [64,128)
    const int u  = t & 255;
    const int vg = u & 31;          // vocab lane; row v = v0 + vi*32 + vg
    const int bg = u >> 5;          // batch group (4 batches each)
    // stage fc_w slice into LDS once (reused for all 128 steps)
    for (int i = t; i < VW*HH_; i += 512){
      const int r = i >> 7, k = i & 127;
      ((float*)lw4)[((k >> 2)*VW + r)*4 + (k & 3)] = fcw[(size_t)(v0 + r)*HH_ + k];
    }
    float fb[5];
#pragma unroll
    for (int vi = 0; vi < 5; ++vi) fb[vi] = fcb[v0 + vi*32 + vg];
    __syncthreads();
#pragma unroll 1
    for (int s = 1; s <= TT_; ++s){
      if (t < 32)
        while (__hip_atomic_load(&h_flag[t], __ATOMIC_ACQUIRE, __HIP_MEMORY_SCOPE_AGENT) != (unsigned)s)
          __builtin_amdgcn_s_sleep(2);
      __syncthreads();
      // stage h (device-scope loads bypass stale caches)
      for (int i = t; i < BB_*HH_; i += 512){
        const float hv = __hip_atomic_load(&h_dec[i], __ATOMIC_RELAXED, __HIP_MEMORY_SCOPE_AGENT);
        const int bb = i >> 7, k = i & 127;
        ((float*)lh4)[((k >> 2)*BB_ + bb)*4 + (k & 3)] = hv;
      }
      __syncthreads();
      float acc[5][4];
#pragma unroll
      for (int vi = 0; vi < 5; ++vi)
#pragma unroll
        for (int bi = 0; bi < 4; ++bi) acc[vi][bi] = 0.f;
      const int kb = ks * 16;
#pragma unroll 4
      for (int kc = 0; kc < 16; ++kc){
        const int kcc = kb + kc;
        const float4 hb0 = lh4[kcc*BB_ + bg*4 + 0];
        const float4 hb1 = lh4[kcc*BB_ + bg*4 + 1];
        const float4 hb2 = lh4[kcc*BB_ + bg*4 + 2];
        const float4 hb3 = lh4[kcc*BB_ + bg*4 + 3];
#pragma unroll
        for (int vi = 0; vi < 5; ++vi){
          const float4 w = lw4[kcc*VW + vi*32 + vg];
          acc[vi][0] = fmaf(w.x,hb0.x,fmaf(w.y,hb0.y,fmaf(w.z,hb0.z,fmaf(w.w,hb0.w,acc[vi][0]))));
          acc[vi][1] = fmaf(w.x,hb1.x,fmaf(w.y,hb1.y,fmaf(w.z,hb1.z,fmaf(w.w,hb1.w,acc[vi][1]))));
          acc[vi][2] = fmaf(w.x,hb2.x,fmaf(w.y,hb2.y,fmaf(w.z,hb2.z,fmaf(w.w,hb2.w,acc[vi][2]))));
          acc[vi][3] = fmaf(w.x,hb3.x,fmaf(w.y,hb3.y,fmaf(w.z,hb3.z,fmaf(w.w,hb3.w,acc[vi][3]))));
        }
      }
      // k-split reduce: ks=1 half publishes, ks=0 half combines
      if (ks == 1){
#pragma unroll
        for (int vi = 0; vi < 5; ++vi)
#pragma unroll
          for (int bi = 0; bi < 4; ++bi) rdf[u*21 + vi*4 + bi] = acc[vi][bi];
      }
      __syncthreads();
      if (ks == 0){
#pragma unroll
        for (int bi = 0; bi < 4; ++bi){
          const int bb = bg*4 + bi;
          float* orow = out + ((size_t)bb*TT_ + (s-1))*(size_t)VV_ + v0;
          unsigned long long best = 0ull;
#pragma unroll
          for (int vi = 0; vi < 5; ++vi){
            const float val = acc[vi][bi] + rdf[u*21 + vi*4 + bi] + fb[vi];
            orow[vi*32 + vg] = val;
            const unsigned long long pk = packmax(val, v0 + vi*32 + vg);
            if (pk > best) best = pk;
          }
          pb[bb*33 + vg] = best;
        }
      }
      __syncthreads();
      if (t < 32){
        unsigned long long m = 0ull;
#pragma unroll 1
        for (int j = 0; j < 32; ++j){ const unsigned long long o = pb[t*33 + j]; if (o > m) m = o; }
        __hip_atomic_store(&part[(size_t)widx*32 + t], m, __ATOMIC_RELAXED, __HIP_MEMORY_SCOPE_AGENT);
      }
      __threadfence();
      __syncthreads();
      if (t == 0) __hip_atomic_store(&mm_flag[widx], (unsigned)s, __ATOMIC_RELEASE, __HIP_MEMORY_SCOPE_AGENT);
    }
  }
}

extern "C" void kernel_launch(void* const* d_in, const int* in_sizes, int n_in,
                              void* d_out, int out_size, void* d_ws, size_t ws_size,
                              hipStream_t stream){
  (void)in_sizes; (void)n_in; (void)out_size; (void)ws_size;
  const int*   x     = (const int*)  d_in[0];
  const float* embed = (const float*)d_in[1];
  const float* eWih  = (const float*)d_in[2];
  const float* eWhh  = (const float*)d_in[3];
  const float* eb    = (const float*)d_in[4];
  const float* dWih  = (const float*)d_in[5];
  const float* dWhh  = (const float*)d_in[6];
  const float* db    = (const float*)d_in[7];
  const float* fcw   = (const float*)d_in[8];
  const float* fcb   = (const float*)d_in[9];
  float* out = (float*)d_out;
  char* ws = (char*)d_ws;
  unsigned long long* part = (unsigned long long*)(ws + WS_PART);
  float* h_dec = (float*)(ws + WS_HDEC);
  float* h_enc = (float*)(ws + WS_HENC);
  float* c_enc = (float*)(ws + WS_CENC);
  unsigned* mm_flag = (unsigned*)(ws + WS_MMF);
  unsigned* h_flag  = (unsigned*)(ws + WS_HF);

  // zero handshake flags every launch (captured as a graph node -> deterministic replays)
  hipMemsetAsync(ws + WS_MMF, 0, WS_END - WS_MMF, stream);
  // allow >64KB dynamic LDS (gfx950 has 160KB/CU); idempotent host-side call
  hipFuncSetAttribute((const void*)dec_kernel, hipFuncAttributeMaxDynamicSharedMemorySize, DYN_LDS);

  enc_kernel<<<NCELL, 512, 0, stream>>>(x, embed, eWih, eWhh, eb, h_enc, c_enc);
  dec_kernel<<<NWG, 512, DYN_LDS, stream>>>(embed, dWih, dWhh, db, fcw, fcb,
                                            h_enc, c_enc, h_dec, mm_flag, h_flag, part, out);
}